// Round 10
// baseline (81.638 us; speedup 1.0000x reference)
//
#include <hip/hip_runtime.h>

// PolyLinear: out[i] = b + sum_j W[j] * prod_k x_aug[i, idx[j,k]]
// Deterministic lex-order enumeration: deg1 W[0..31], deg2 W[32..559] (a<=b),
// deg3 W[560..6543] (a<=b<=c). Factorization per row:
//   acc = sum_a W1[a]*x_a
//       + sum_{a<=b} (x_a*x_b) * ( W2[a,b] + sum_{c>=b} W3[a,b,c]*x_c )
//
// V10. Proven design cell (9 rounds): weights in LDS + R=2 rows/thread is
// the only spill-free, non-drain-bound combination (SMEM path drain-bound
// 44us; LDS R=4 always spills). V9 = that cell + all-4-waves-same-part
// (I$-resident) + NPART=16 + 1024 blocks (4/CU TLP) — kernel ~20us est.
// V9's suspected remaining cost: 524k device-scope atomicAdds where each
// output line is hammered by 16 blocks on different XCDs (cross-XCD L2
// line ping-pong). V10 replaces atomics with a two-stage reduce:
//   stage1: partial[part][row] -> d_ws, plain coalesced stores (2MB).
//   stage2: out[row] = b + sum_p partial[p][row] (128 blocks, ~3us).
// Fallback to the proven atomic path if ws_size < 2MB.
// Floor: LDS pipe ~1636 ds_read_b128/CU x ~12cy ~ 8.2us; VALU ~2.9us.

#define NPART 16
#define TOTAL3 5984

__device__ __forceinline__ constexpr int off2(int a, int b) {
    // deg2 base 32; pairs (a<=b) lex order
    return 32 + 32 * a - (a * (a - 1)) / 2 + (b - a);
}

__device__ __forceinline__ constexpr int off3(int a, int b, int c) {
    // deg3 base 560; triples (a<=b<=c) lex order.
    // g3[a] = #triples with first index < a
    constexpr int g3[32] = {
        0,    528,  1024, 1489, 1924, 2330, 2708, 3059,
        3384, 3684, 3960, 4213, 4444, 4654, 4844, 5015,
        5168, 5304, 5424, 5529, 5620, 5698, 5764, 5819,
        5864, 5900, 5928, 5949, 5964, 5974, 5980, 5983};
    return 560 + g3[a] + 32 * (b - a) - ((b * (b - 1)) / 2 - (a * (a - 1)) / 2) + (c - b);
}

// #deg3 triples strictly before pair (a,b)'s c-run in lex order
__device__ __forceinline__ constexpr int cum3(int a, int b) {
    return off3(a, b, b) - 560;
}

// Balanced static ownership of pair (a,b): parts get ~equal deg3-FMA counts.
__device__ __forceinline__ constexpr int owner_of(int a, int b) {
    return (cum3(a, b) * NPART) / TOTAL3;  // monotone, 0..NPART-1
}

template <int PART>
__device__ __forceinline__ void eval_part2(const float* __restrict__ Wl,
                                           const float (&x0)[32],
                                           const float (&x1)[32],
                                           float& r0, float& r1) {
    float a0 = 0.0f, a1 = 0.0f;
#pragma unroll
    for (int a = 0; a < 32; ++a) {
#pragma unroll
        for (int b = a; b < 32; ++b) {
            if (owner_of(a, b) == PART) {  // compile-time filter
                if (a == b) {  // attach deg1 term for feature a here
                    const float w1 = Wl[a];
                    a0 = __builtin_fmaf(w1, x0[a], a0);
                    a1 = __builtin_fmaf(w1, x1[a], a1);
                }
                const float w2 = Wl[off2(a, b)];  // deg2 weight seeds chains
                float s0 = w2, s1 = w2;
#pragma unroll
                for (int c = b; c < 32; ++c) {
                    const float w = Wl[off3(a, b, c)];  // 1 LDS read, 2 FMAs
                    s0 = __builtin_fmaf(w, x0[c], s0);
                    s1 = __builtin_fmaf(w, x1[c], s1);
                }
                a0 = __builtin_fmaf(x0[a] * x0[b], s0, a0);
                a1 = __builtin_fmaf(x1[a] * x1[b], s1, a1);
            }
        }
    }
    r0 = a0;
    r1 = a1;
}

// Shared body: compute this thread's (r0, r1) for rows rbase, rbase+256.
template <int WRITE_ATOMIC>
__device__ __forceinline__ void poly_body(const float* __restrict__ X,
                                          const float* __restrict__ W,
                                          const float* __restrict__ Bp,
                                          float* __restrict__ dst,  // P or out
                                          int rows) {
    const int part = blockIdx.x >> 6;  // 0..15 (adjacent blocks share part)
    const int tile = blockIdx.x & 63;  // 0..63
    const long rbase = (long)tile * 512 + threadIdx.x;

    __shared__ float Wl[6544];  // 26.2 KB staged weights

    {
        const float4* Wg = (const float4*)W;
        float4* Wd = (float4*)Wl;
        for (int i = threadIdx.x; i < 1636; i += 256) Wd[i] = Wg[i];
    }

    float x0[32], x1[32];
    {
        const float4* p0 = (const float4*)(X + (rbase) * 32);
        const float4* p1 = (const float4*)(X + (rbase + 256) * 32);
#pragma unroll
        for (int i = 0; i < 8; ++i) {
            const float4 a = p0[i];
            x0[4 * i + 0] = a.x; x0[4 * i + 1] = a.y;
            x0[4 * i + 2] = a.z; x0[4 * i + 3] = a.w;
            const float4 b = p1[i];
            x1[4 * i + 0] = b.x; x1[4 * i + 1] = b.y;
            x1[4 * i + 2] = b.z; x1[4 * i + 3] = b.w;
        }
    }
    __syncthreads();  // Wl ready

    float r0 = 0.0f, r1 = 0.0f;
#define EVAL_CASE(P) \
    case P: eval_part2<P>(Wl, x0, x1, r0, r1); break;
    switch (part) {
        EVAL_CASE(0)  EVAL_CASE(1)  EVAL_CASE(2)  EVAL_CASE(3)
        EVAL_CASE(4)  EVAL_CASE(5)  EVAL_CASE(6)  EVAL_CASE(7)
        EVAL_CASE(8)  EVAL_CASE(9)  EVAL_CASE(10) EVAL_CASE(11)
        EVAL_CASE(12) EVAL_CASE(13) EVAL_CASE(14) EVAL_CASE(15)
    }
#undef EVAL_CASE

    if (WRITE_ATOMIC) {
        const float badd = (part == 0) ? Bp[0] : 0.0f;
        atomicAdd(&dst[rbase], r0 + badd);
        atomicAdd(&dst[rbase + 256], r1 + badd);
    } else {
        // Plain coalesced stores to partial[part][row] — no contention.
        dst[(long)part * rows + rbase] = r0;
        dst[(long)part * rows + rbase + 256] = r1;
    }
}

__global__ __launch_bounds__(256) void PolyLinear_40218073760341_stage1(
    const float* __restrict__ X, const float* __restrict__ W,
    const float* __restrict__ Bp, float* __restrict__ P, int rows) {
    poly_body<0>(X, W, Bp, P, rows);
}

__global__ __launch_bounds__(256) void PolyLinear_40218073760341_atomic(
    const float* __restrict__ X, const float* __restrict__ W,
    const float* __restrict__ Bp, float* __restrict__ out, int rows) {
    poly_body<1>(X, W, Bp, out, rows);
}

// Stage 2: out[row] = b + sum_p P[p][row]. Coalesced per-slice reads.
__global__ __launch_bounds__(256) void PolyLinear_40218073760341_reduce(
    const float* __restrict__ P, const float* __restrict__ Bp,
    float* __restrict__ out, int rows) {
    const int row = blockIdx.x * 256 + threadIdx.x;
    float r = Bp[0];
#pragma unroll
    for (int p = 0; p < NPART; ++p) r += P[(long)p * rows + row];
    out[row] = r;
}

extern "C" void kernel_launch(void* const* d_in, const int* in_sizes, int n_in,
                              void* d_out, int out_size, void* d_ws, size_t ws_size,
                              hipStream_t stream) {
    const float* X  = (const float*)d_in[0];  // (32768, 32) fp32
    const float* W  = (const float*)d_in[1];  // (1, 6544) fp32
    const float* Bp = (const float*)d_in[2];  // (1,) fp32
    // d_in[3] = idx — deterministic, unused.
    float* out = (float*)d_out;

    const int rows = in_sizes[0] / 32;            // 32768
    const int grid = NPART * (rows / 512);        // 16 parts x 64 tiles
    const size_t need = (size_t)NPART * rows * sizeof(float);  // 2 MB

    if (d_ws != nullptr && ws_size >= need) {
        float* P = (float*)d_ws;
        PolyLinear_40218073760341_stage1<<<grid, 256, 0, stream>>>(X, W, Bp, P, rows);
        PolyLinear_40218073760341_reduce<<<rows / 256, 256, 0, stream>>>(P, Bp, out, rows);
    } else {
        hipMemsetAsync(out, 0, (size_t)rows * sizeof(float), stream);
        PolyLinear_40218073760341_atomic<<<grid, 256, 0, stream>>>(X, W, Bp, out, rows);
    }
}

// Round 11
// 72.315 us; speedup vs baseline: 1.1289x; 1.1289x over previous
//
#include <hip/hip_runtime.h>

// PolyLinear: out[i] = b + sum_j W[j] * prod_k x_aug[i, idx[j,k]]
// Deterministic lex-order enumeration: deg1 W[0..31], deg2 W[32..559] (a<=b),
// deg3 W[560..6543] (a<=b<=c). Factorization per row:
//   acc = sum_a W1[a]*x_a
//       + sum_{a<=b} (x_a*x_b) * ( W2[a,b] + sum_{c>=b} W3[a,b,c]*x_c )
//
// V11. Ten rounds of evidence:
//   - weights MUST ride LDS (SMEM path drain-bound: 44us @ 15% VALUBusy).
//   - R (rows/thread) = 2 is the spill-free maximum (R=4 spilled at every
//     cap: x[128] + in-flight ds_read quads > 256 VGPR; sched_barrier(0)
//     didn't bound it).
//   - single-dispatch, block-computes-complete-rows wins: V4 (71.2us bench)
//     beat V9/V10 multi-dispatch part-split (80.8/81.6us) — atomics were
//     NOT the cost (V10 two-stage == V9 atomic); the extra dispatch, 16x X
//     re-fetch, and 2x W staging were.
// V11 = V4 skeleton with halved per-CU LDS traffic:
//   512-thr blocks (8 waves), NPART=8 pair-balanced owner_of split, R=2
//   -> block covers 128 rows, grid = 256 = exactly 1 block/CU;
//   per-CU: 1636 ds_read_b128 (half of V4's 3272), W staged once (not 2x),
//   X fetched once. VGPR demand ~100 < 128-cap (512-thr rule) -> no spill.
//   Single dispatch, bias in the LDS-reduce epilogue.

#define NPART 8
#define TOTAL3 5984

__device__ __forceinline__ constexpr int off2(int a, int b) {
    // deg2 base 32; pairs (a<=b) lex order
    return 32 + 32 * a - (a * (a - 1)) / 2 + (b - a);
}

__device__ __forceinline__ constexpr int off3(int a, int b, int c) {
    // deg3 base 560; triples (a<=b<=c) lex order.
    // g3[a] = #triples with first index < a
    constexpr int g3[32] = {
        0,    528,  1024, 1489, 1924, 2330, 2708, 3059,
        3384, 3684, 3960, 4213, 4444, 4654, 4844, 5015,
        5168, 5304, 5424, 5529, 5620, 5698, 5764, 5819,
        5864, 5900, 5928, 5949, 5964, 5974, 5980, 5983};
    return 560 + g3[a] + 32 * (b - a) - ((b * (b - 1)) / 2 - (a * (a - 1)) / 2) + (c - b);
}

// #deg3 triples strictly before pair (a,b)'s c-run in lex order
__device__ __forceinline__ constexpr int cum3(int a, int b) {
    return off3(a, b, b) - 560;
}

// Balanced static ownership of pair (a,b): parts get ~equal deg3-FMA counts.
__device__ __forceinline__ constexpr int owner_of(int a, int b) {
    return (cum3(a, b) * NPART) / TOTAL3;  // monotone, 0..NPART-1
}

template <int PART>
__device__ __forceinline__ void eval_part2(const float* __restrict__ Wl,
                                           const float (&x0)[32],
                                           const float (&x1)[32],
                                           float& r0, float& r1) {
    float a0 = 0.0f, a1 = 0.0f;
#pragma unroll
    for (int a = 0; a < 32; ++a) {
#pragma unroll
        for (int b = a; b < 32; ++b) {
            if (owner_of(a, b) == PART) {  // compile-time filter
                if (a == b) {  // attach deg1 term for feature a here
                    const float w1 = Wl[a];
                    a0 = __builtin_fmaf(w1, x0[a], a0);
                    a1 = __builtin_fmaf(w1, x1[a], a1);
                }
                const float w2 = Wl[off2(a, b)];  // deg2 weight seeds chains
                float s0 = w2, s1 = w2;
#pragma unroll
                for (int c = b; c < 32; ++c) {
                    const float w = Wl[off3(a, b, c)];  // 1 LDS read, 2 FMAs
                    s0 = __builtin_fmaf(w, x0[c], s0);
                    s1 = __builtin_fmaf(w, x1[c], s1);
                }
                a0 = __builtin_fmaf(x0[a] * x0[b], s0, a0);
                a1 = __builtin_fmaf(x1[a] * x1[b], s1, a1);
            }
        }
    }
    r0 = a0;
    r1 = a1;
}

// Block: 512 threads = 8 waves. Wave w computes part w of the SAME 128 rows
// (lane owns rows base+lane, base+64+lane). LDS reduce across waves, single
// coalesced store. grid = rows/128 = 256 = 1 block/CU.
__global__ __launch_bounds__(512) void PolyLinear_40218073760341_kernel(
    const float* __restrict__ X,   // (rows, 32)
    const float* __restrict__ W,   // (6544,)
    const float* __restrict__ Bp,  // (1,)
    float* __restrict__ out)       // (rows,)
{
    const int lane = threadIdx.x & 63;
    const int wave = threadIdx.x >> 6;  // part id 0..7
    const long base = (long)blockIdx.x * 128;

    __shared__ float Wl[6544];         // 26.2 KB staged weights
    __shared__ float partial[8][128];  // 4 KB reduce buffer

    // Stage W -> LDS (coalesced float4; 1636 vec4 over 512 threads)
    {
        const float4* Wg = (const float4*)W;
        float4* Wd = (float4*)Wl;
        for (int i = threadIdx.x; i < 1636; i += 512) Wd[i] = Wg[i];
    }

    // Load this lane's 2 rows (all waves read the same 128 rows; L1-hit
    // after the first wave touches them).
    float x0[32], x1[32];
    {
        const float4* p0 = (const float4*)(X + (base + lane) * 32);
        const float4* p1 = (const float4*)(X + (base + 64 + lane) * 32);
#pragma unroll
        for (int i = 0; i < 8; ++i) {
            const float4 a = p0[i];
            x0[4 * i + 0] = a.x; x0[4 * i + 1] = a.y;
            x0[4 * i + 2] = a.z; x0[4 * i + 3] = a.w;
            const float4 b = p1[i];
            x1[4 * i + 0] = b.x; x1[4 * i + 1] = b.y;
            x1[4 * i + 2] = b.z; x1[4 * i + 3] = b.w;
        }
    }
    __syncthreads();  // Wl ready

    float r0 = 0.0f, r1 = 0.0f;
#define EVAL_CASE(P) \
    case P: eval_part2<P>(Wl, x0, x1, r0, r1); break;
    switch (wave) {
        EVAL_CASE(0) EVAL_CASE(1) EVAL_CASE(2) EVAL_CASE(3)
        EVAL_CASE(4) EVAL_CASE(5) EVAL_CASE(6) EVAL_CASE(7)
    }
#undef EVAL_CASE

    partial[wave][lane] = r0;
    partial[wave][64 + lane] = r1;
    __syncthreads();

    if (threadIdx.x < 128) {
        float r = Bp[0];
#pragma unroll
        for (int w = 0; w < 8; ++w) r += partial[w][threadIdx.x];
        out[base + threadIdx.x] = r;
    }
}

extern "C" void kernel_launch(void* const* d_in, const int* in_sizes, int n_in,
                              void* d_out, int out_size, void* d_ws, size_t ws_size,
                              hipStream_t stream) {
    const float* X  = (const float*)d_in[0];  // (32768, 32) fp32
    const float* W  = (const float*)d_in[1];  // (1, 6544) fp32
    const float* Bp = (const float*)d_in[2];  // (1,) fp32
    // d_in[3] = idx — deterministic, unused.
    float* out = (float*)d_out;

    const int rows = in_sizes[0] / 32;  // 32768
    const int grid = rows / 128;        // 256 blocks of 512 threads
    PolyLinear_40218073760341_kernel<<<grid, 512, 0, stream>>>(X, W, Bp, out);
}